// Round 1
// baseline (1183.906 us; speedup 1.0000x reference)
//
#include <hip/hip_runtime.h>

typedef _Float16 half8 __attribute__((ext_vector_type(8)));
typedef _Float16 half4 __attribute__((ext_vector_type(4)));
typedef float f4 __attribute__((ext_vector_type(4)));

#define LDSTRIDE 40  // 32 + 8 pad (halves)

// ---------------------------------------------------------------------------
// Weight transpose+cast: W fp32 [1024(k)][1024(n)] -> Wt fp16 [1024(n)][1024(k)]
// ---------------------------------------------------------------------------
__global__ void transpose_cast6(const float* __restrict__ W0, const float* __restrict__ W1,
                                const float* __restrict__ W2, const float* __restrict__ W3,
                                const float* __restrict__ W4, const float* __restrict__ W5,
                                _Float16* __restrict__ Wt)
{
    const float* Ws[6] = {W0, W1, W2, W3, W4, W5};
    const float* W = Ws[blockIdx.z];
    _Float16* O = Wt + (size_t)blockIdx.z * (1024u * 1024u);

    __shared__ _Float16 t[64][72];
    const int tid = threadIdx.x;
    const int n0 = blockIdx.x * 64;
    const int k0 = blockIdx.y * 64;

    #pragma unroll
    for (int i = 0; i < 4; ++i) {
        int idx = tid + i * 256;
        int r = idx >> 4;        // k within tile
        int c4 = idx & 15;       // n chunk
        f4 v = *(const f4*)(W + (size_t)(k0 + r) * 1024 + n0 + c4 * 4);
        #pragma unroll
        for (int j = 0; j < 4; ++j) t[r][c4 * 4 + j] = (_Float16)v[j];
    }
    __syncthreads();
    #pragma unroll
    for (int i = 0; i < 4; ++i) {
        int idx = tid + i * 256;
        int r = idx >> 4;        // n within tile
        int c4 = idx & 15;       // k chunk
        half4 h;
        #pragma unroll
        for (int j = 0; j < 4; ++j) h[j] = t[c4 * 4 + j][r];
        *(half4*)(O + (size_t)(n0 + r) * 1024 + k0 + c4 * 4) = h;
    }
}

// ---------------------------------------------------------------------------
// Generic B^T GEMM: C[M,N] = A[M,K] * Bt[N,K]^T
// AMODE: 0 = A fp16, 1 = A fp32 (convert during staging)
// OMODE: 0 = fp16 row-major, 1 = fp32 row-major, 2 = fp16 transposed (Vt[b][e][t])
// 128x128 tile, BK=32, 4 waves (2x2), each wave 64x64 via 4x4 frags of 16x16x32.
// ---------------------------------------------------------------------------
template<int AMODE, int OMODE>
__global__ __launch_bounds__(256)
void gemm_bt(const void* __restrict__ Ain, const _Float16* __restrict__ Btin,
             void* __restrict__ Cout, int lda, int ldb, int ldc, int K,
             long sAz, long sBz, long sCz, float scale)
{
    __shared__ _Float16 As[2][128 * LDSTRIDE];
    __shared__ _Float16 Bs[2][128 * LDSTRIDE];

    const int tid  = threadIdx.x;
    const int lane = tid & 63;
    const int wid  = tid >> 6;
    const int wr   = wid >> 1;
    const int wc   = wid & 1;
    const int z    = blockIdx.z;
    const int n0   = blockIdx.x * 128;
    const int m0   = blockIdx.y * 128;

    const _Float16* Bt = Btin + (size_t)z * sBz;

    // staging mapping: 512 chunks of 8 elems (128 rows x 4 chunks); 2 per thread
    const int sr0 = tid >> 2;
    const int sk  = (tid & 3) * 8;

    f4 acc[4][4];
    #pragma unroll
    for (int m = 0; m < 4; ++m)
        #pragma unroll
        for (int n = 0; n < 4; ++n)
            acc[m][n] = f4{0.f, 0.f, 0.f, 0.f};

    const int KT = K >> 5;

    f4    ra[2][2];   // AMODE==1
    half8 rah[2];     // AMODE==0
    half8 rbh[2];

    auto loadTile = [&](int kt) {
        #pragma unroll
        for (int i = 0; i < 2; ++i) {
            int r = sr0 + i * 64;
            if (AMODE == 1) {
                const float* ap = (const float*)Ain + (size_t)z * sAz + (size_t)(m0 + r) * lda + kt * 32 + sk;
                ra[i][0] = *(const f4*)ap;
                ra[i][1] = *(const f4*)(ap + 4);
            } else {
                const _Float16* ap = (const _Float16*)Ain + (size_t)z * sAz + (size_t)(m0 + r) * lda + kt * 32 + sk;
                rah[i] = *(const half8*)ap;
            }
            const _Float16* bp = Bt + (size_t)(n0 + r) * ldb + kt * 32 + sk;
            rbh[i] = *(const half8*)bp;
        }
    };
    auto writeLDS = [&](int buf) {
        #pragma unroll
        for (int i = 0; i < 2; ++i) {
            int r = sr0 + i * 64;
            half8 h;
            if (AMODE == 1) {
                #pragma unroll
                for (int j = 0; j < 4; ++j) { h[j] = (_Float16)ra[i][0][j]; h[4 + j] = (_Float16)ra[i][1][j]; }
            } else {
                h = rah[i];
            }
            *(half8*)&As[buf][r * LDSTRIDE + sk] = h;
            *(half8*)&Bs[buf][r * LDSTRIDE + sk] = rbh[i];
        }
    };

    const int lr = lane & 15;
    const int lk = (lane >> 4) * 8;
    const int abase = (wr * 64 + lr) * LDSTRIDE + lk;
    const int bbase = (wc * 64 + lr) * LDSTRIDE + lk;

    loadTile(0);
    writeLDS(0);
    __syncthreads();

    int cur = 0;
    for (int kt = 0; kt < KT; ++kt) {
        if (kt + 1 < KT) loadTile(kt + 1);

        half8 af[4], bf[4];
        #pragma unroll
        for (int m = 0; m < 4; ++m) af[m] = *(const half8*)&As[cur][abase + m * 16 * LDSTRIDE];
        #pragma unroll
        for (int n = 0; n < 4; ++n) bf[n] = *(const half8*)&Bs[cur][bbase + n * 16 * LDSTRIDE];
        #pragma unroll
        for (int m = 0; m < 4; ++m)
            #pragma unroll
            for (int n = 0; n < 4; ++n)
                acc[m][n] = __builtin_amdgcn_mfma_f32_16x16x32_f16(af[m], bf[n], acc[m][n], 0, 0, 0);

        if (kt + 1 < KT) writeLDS(cur ^ 1);
        __syncthreads();
        cur ^= 1;
    }

    const int orow0 = m0 + wr * 64 + (lane >> 4) * 4;  // + m*16 + r
    const int ocol0 = n0 + wc * 64 + lr;               // + n*16

    if constexpr (OMODE == 0) {
        _Float16* C = (_Float16*)Cout + (size_t)z * sCz;
        #pragma unroll
        for (int m = 0; m < 4; ++m)
            #pragma unroll
            for (int r = 0; r < 4; ++r) {
                size_t row = (size_t)(orow0 + m * 16 + r);
                #pragma unroll
                for (int n = 0; n < 4; ++n)
                    C[row * ldc + ocol0 + n * 16] = (_Float16)(acc[m][n][r] * scale);
            }
    } else if constexpr (OMODE == 1) {
        float* C = (float*)Cout + (size_t)z * sCz;
        #pragma unroll
        for (int m = 0; m < 4; ++m)
            #pragma unroll
            for (int r = 0; r < 4; ++r) {
                size_t row = (size_t)(orow0 + m * 16 + r);
                #pragma unroll
                for (int n = 0; n < 4; ++n)
                    C[row * ldc + ocol0 + n * 16] = acc[m][n][r] * scale;
            }
    } else {
        // Vt[b][e][t], b from global row (batch stride 2048 rows), e = col, t = row%2048
        _Float16* C = (_Float16*)Cout;
        const size_t bofs = (size_t)(m0 >> 11) * (1024ull * 2048ull);
        const int t0 = orow0 & 2047;
        #pragma unroll
        for (int n = 0; n < 4; ++n) {
            size_t e = (size_t)(ocol0 + n * 16);
            #pragma unroll
            for (int m = 0; m < 4; ++m) {
                half4 h;
                #pragma unroll
                for (int r = 0; r < 4; ++r) h[r] = (_Float16)acc[m][n][r];
                *(half4*)(C + bofs + e * 2048 + (t0 + m * 16)) = h;
            }
        }
    }
}

// ---------------------------------------------------------------------------
// In-place row softmax on S fp16 [nrows][2048]; 1 wave per row, all-register.
// ---------------------------------------------------------------------------
__global__ void softmax_rows(_Float16* __restrict__ S)
{
    const int wid  = threadIdx.x >> 6;
    const int lane = threadIdx.x & 63;
    const size_t row = (size_t)blockIdx.x * 4 + wid;
    _Float16* p = S + row * 2048;

    float v[32];
    #pragma unroll
    for (int i = 0; i < 4; ++i) {
        half8 h = *(const half8*)(p + i * 512 + lane * 8);
        #pragma unroll
        for (int j = 0; j < 8; ++j) v[i * 8 + j] = (float)h[j];
    }
    float m = -1e30f;
    #pragma unroll
    for (int t = 0; t < 32; ++t) m = fmaxf(m, v[t]);
    #pragma unroll
    for (int mask = 1; mask < 64; mask <<= 1) m = fmaxf(m, __shfl_xor(m, mask));

    float s = 0.f;
    #pragma unroll
    for (int t = 0; t < 32; ++t) { v[t] = __expf(v[t] - m); s += v[t]; }
    #pragma unroll
    for (int mask = 1; mask < 64; mask <<= 1) s += __shfl_xor(s, mask);
    const float r = 1.0f / s;

    #pragma unroll
    for (int i = 0; i < 4; ++i) {
        half8 h;
        #pragma unroll
        for (int j = 0; j < 8; ++j) h[j] = (_Float16)(v[i * 8 + j] * r);
        *(half8*)(p + i * 512 + lane * 8) = h;
    }
}

// ---------------------------------------------------------------------------
extern "C" void kernel_launch(void* const* d_in, const int* in_sizes, int n_in,
                              void* d_out, int out_size, void* d_ws, size_t ws_size,
                              hipStream_t stream)
{
    const float* x1 = (const float*)d_in[0];
    const float* x2 = (const float*)d_in[1];
    // weight order in d_in: Wq1, Wk1, Wv1, Wq2, Wk2, Wv2  (d_in[2..7])

    char* ws = (char*)d_ws;
    _Float16* Wt = (_Float16*)ws;                                   // 6 x 1M halves (12 MB)
    _Float16* Q  = (_Float16*)(ws + 12582912);                      // 32 MB
    _Float16* Kk = (_Float16*)(ws + 12582912 + 33554432L);          // 32 MB
    _Float16* Vt = (_Float16*)(ws + 12582912 + 2 * 33554432L);      // 32 MB
    _Float16* S  = (_Float16*)(ws + 12582912 + 3 * 33554432L);      // 64 MB

    transpose_cast6<<<dim3(16, 16, 6), 256, 0, stream>>>(
        (const float*)d_in[2], (const float*)d_in[3], (const float*)d_in[4],
        (const float*)d_in[5], (const float*)d_in[6], (const float*)d_in[7], Wt);

    for (int d = 0; d < 2; ++d) {
        // d==0: context_vec_2 = attn(Q=x1·Wq1, K=x2·Wk2, V=x2·Wv2) -> out[16777216:]
        // d==1: context_vec_1 = attn(Q=x2·Wq2, K=x1·Wk1, V=x1·Wv1) -> out[0:]
        const float* xq  = (d == 0) ? x1 : x2;
        const float* xkv = (d == 0) ? x2 : x1;
        const _Float16* wtq = Wt + (size_t)((d == 0) ? 0 : 3) * 1048576;
        const _Float16* wtk = Wt + (size_t)((d == 0) ? 4 : 1) * 1048576;
        const _Float16* wtv = Wt + (size_t)((d == 0) ? 5 : 2) * 1048576;
        float* outp = (float*)d_out + ((d == 0) ? 16777216L : 0L);

        gemm_bt<1, 0><<<dim3(8, 128, 1), 256, 0, stream>>>(xq,  wtq, Q,  1024, 1024, 1024, 1024, 0, 0, 0, 1.f);
        gemm_bt<1, 0><<<dim3(8, 128, 1), 256, 0, stream>>>(xkv, wtk, Kk, 1024, 1024, 1024, 1024, 0, 0, 0, 1.f);
        gemm_bt<1, 2><<<dim3(8, 128, 1), 256, 0, stream>>>(xkv, wtv, Vt, 1024, 1024, 0,    1024, 0, 0, 0, 1.f);

        gemm_bt<0, 0><<<dim3(16, 16, 8), 256, 0, stream>>>(Q, Kk, S, 1024, 1024, 2048, 1024,
                                                           2048L * 1024, 2048L * 1024, 2048L * 2048, 0.03125f);
        softmax_rows<<<4096, 256, 0, stream>>>(S);

        gemm_bt<0, 1><<<dim3(8, 16, 8), 256, 0, stream>>>(S, Vt, outp, 2048, 2048, 1024, 2048,
                                                          2048L * 2048, 2048L * 1024, 2048L * 1024, 1.f);
    }
}

// Round 3
// 982.217 us; speedup vs baseline: 1.2053x; 1.2053x over previous
//
#include <hip/hip_runtime.h>

typedef _Float16 half8 __attribute__((ext_vector_type(8)));
typedef _Float16 half4 __attribute__((ext_vector_type(4)));
typedef float f4 __attribute__((ext_vector_type(4)));

__device__ __forceinline__ void gload16(const void* g, void* l) {
    __builtin_amdgcn_global_load_lds(
        (const __attribute__((address_space(1))) void*)g,
        (__attribute__((address_space(3))) void*)l, 16, 0, 0);
}

// ---------------------------------------------------------------------------
// Weight transpose+cast: W fp32 [1024(k)][1024(n)] -> Wt fp16 [1024(n)][1024(k)]
// ---------------------------------------------------------------------------
__global__ void transpose_cast6(const float* __restrict__ W0, const float* __restrict__ W1,
                                const float* __restrict__ W2, const float* __restrict__ W3,
                                const float* __restrict__ W4, const float* __restrict__ W5,
                                _Float16* __restrict__ Wt)
{
    const float* Ws[6] = {W0, W1, W2, W3, W4, W5};
    const float* W = Ws[blockIdx.z];
    _Float16* O = Wt + (size_t)blockIdx.z * (1024u * 1024u);

    __shared__ _Float16 t[64][72];
    const int tid = threadIdx.x;
    const int n0 = blockIdx.x * 64;
    const int k0 = blockIdx.y * 64;

    #pragma unroll
    for (int i = 0; i < 4; ++i) {
        int idx = tid + i * 256;
        int r = idx >> 4;
        int c4 = idx & 15;
        f4 v = *(const f4*)(W + (size_t)(k0 + r) * 1024 + n0 + c4 * 4);
        #pragma unroll
        for (int j = 0; j < 4; ++j) t[r][c4 * 4 + j] = (_Float16)v[j];
    }
    __syncthreads();
    #pragma unroll
    for (int i = 0; i < 4; ++i) {
        int idx = tid + i * 256;
        int r = idx >> 4;
        int c4 = idx & 15;
        half4 h;
        #pragma unroll
        for (int j = 0; j < 4; ++j) h[j] = t[c4 * 4 + j][r];
        *(half4*)(O + (size_t)(n0 + r) * 1024 + k0 + c4 * 4) = h;
    }
}

// ---------------------------------------------------------------------------
// Cast activations fp32 -> fp16 (two tensors, 16777216 elems each)
// ---------------------------------------------------------------------------
__global__ void cast2_f32_f16(const float* __restrict__ a, const float* __restrict__ b,
                              _Float16* __restrict__ oa, _Float16* __restrict__ ob)
{
    const float* in  = blockIdx.y ? b : a;
    _Float16*   out = blockIdx.y ? ob : oa;
    const size_t stride = (size_t)gridDim.x * 256 * 8;
    for (size_t i = ((size_t)blockIdx.x * 256 + threadIdx.x) * 8; i < 16777216ull; i += stride) {
        f4 v0 = *(const f4*)(in + i);
        f4 v1 = *(const f4*)(in + i + 4);
        half8 h;
        #pragma unroll
        for (int j = 0; j < 4; ++j) { h[j] = (_Float16)v0[j]; h[4 + j] = (_Float16)v1[j]; }
        *(half8*)(out + i) = h;
    }
}

// ---------------------------------------------------------------------------
// m97-structure B^T GEMM: C[M,N] = A[M,K] * Bt[N,K]^T, all fp16 inputs.
// 128x128 tile, BK=32, 4 waves (2x2), global_load_lds width-16 staging,
// linear LDS [128][32], double-buffered, one barrier per K-step.
// OMODE: 0 = fp16 row-major (scaled), 1 = fp32 row-major, 2 = fp16 Vt[b][e][t]
// ---------------------------------------------------------------------------
template<int OMODE>
__global__ __launch_bounds__(256)
void gemm_bt2(const _Float16* __restrict__ Ain, const _Float16* __restrict__ Btin,
              void* __restrict__ Cout, int lda, int ldb, int ldc, int K,
              long sAz, long sBz, long sCz, float scale)
{
    __shared__ alignas(16) _Float16 As[2][128 * 32];
    __shared__ alignas(16) _Float16 Bs[2][128 * 32];

    // T1: bijective XCD swizzle (all grids have nwg % 8 == 0)
    const int nwg = gridDim.x * gridDim.y * gridDim.z;
    const int lid = blockIdx.x + gridDim.x * (blockIdx.y + gridDim.y * blockIdx.z);
    const int cpx = nwg >> 3;
    const int swz = (lid & 7) * cpx + (lid >> 3);
    const int bx  = swz % gridDim.x;
    const int tm  = swz / gridDim.x;
    const int by  = tm % gridDim.y;
    const int bz  = tm / gridDim.y;

    const int tid  = threadIdx.x;
    const int lane = tid & 63;
    const int wid  = tid >> 6;
    const int wr   = wid >> 1;
    const int wc   = wid & 1;
    const int n0   = bx * 128;
    const int m0   = by * 128;

    const _Float16* A  = Ain  + (size_t)bz * sAz;
    const _Float16* Bt = Btin + (size_t)bz * sBz;

    // staging geometry: wave w, round r covers LDS rows [w*16 + r*64, +16),
    // lane covers row w*16 + r*64 + (lane>>2), col halves (lane&3)*8
    const int srow = wid * 16 + (lane >> 2);
    const int scol = (lane & 3) * 8;

    auto stage = [&](int buf, int kt) {
        #pragma unroll
        for (int r = 0; r < 2; ++r) {
            const _Float16* ga = A  + (size_t)(m0 + srow + r * 64) * lda + kt * 32 + scol;
            const _Float16* gb = Bt + (size_t)(n0 + srow + r * 64) * ldb + kt * 32 + scol;
            gload16(ga, &As[buf][wid * 512 + r * 2048]);
            gload16(gb, &Bs[buf][wid * 512 + r * 2048]);
        }
    };

    f4 acc[4][4];
    #pragma unroll
    for (int m = 0; m < 4; ++m)
        #pragma unroll
        for (int n = 0; n < 4; ++n)
            acc[m][n] = f4{0.f, 0.f, 0.f, 0.f};

    const int lr = lane & 15;
    const int lk = (lane >> 4) * 8;
    const int abase = (wr * 64 + lr) * 32 + lk;
    const int bbase = (wc * 64 + lr) * 32 + lk;
    const int KT = K >> 5;

    stage(0, 0);
    __syncthreads();

    int cur = 0;
    for (int kt = 0; kt < KT; ++kt) {
        if (kt + 1 < KT) stage(cur ^ 1, kt + 1);

        half8 af[4], bf[4];
        #pragma unroll
        for (int m = 0; m < 4; ++m) af[m] = *(const half8*)&As[cur][abase + m * 16 * 32];
        #pragma unroll
        for (int n = 0; n < 4; ++n) bf[n] = *(const half8*)&Bs[cur][bbase + n * 16 * 32];
        #pragma unroll
        for (int m = 0; m < 4; ++m)
            #pragma unroll
            for (int n = 0; n < 4; ++n)
                acc[m][n] = __builtin_amdgcn_mfma_f32_16x16x32_f16(af[m], bf[n], acc[m][n], 0, 0, 0);

        __syncthreads();
        cur ^= 1;
    }

    const int orow0 = m0 + wr * 64 + (lane >> 4) * 4;  // + m*16 + r
    const int ocol0 = n0 + wc * 64 + lr;               // + n*16

    if constexpr (OMODE == 0) {
        _Float16* C = (_Float16*)Cout + (size_t)bz * sCz;
        #pragma unroll
        for (int m = 0; m < 4; ++m)
            #pragma unroll
            for (int r = 0; r < 4; ++r) {
                size_t row = (size_t)(orow0 + m * 16 + r);
                #pragma unroll
                for (int n = 0; n < 4; ++n)
                    C[row * ldc + ocol0 + n * 16] = (_Float16)(acc[m][n][r] * scale);
            }
    } else if constexpr (OMODE == 1) {
        float* C = (float*)Cout + (size_t)bz * sCz;
        #pragma unroll
        for (int m = 0; m < 4; ++m)
            #pragma unroll
            for (int r = 0; r < 4; ++r) {
                size_t row = (size_t)(orow0 + m * 16 + r);
                #pragma unroll
                for (int n = 0; n < 4; ++n)
                    C[row * ldc + ocol0 + n * 16] = acc[m][n][r] * scale;
            }
    } else {
        // Vt[b][e][t]: b from global row (2048 rows/batch), e = col, t = row % 2048
        _Float16* C = (_Float16*)Cout;
        const size_t bofs = (size_t)(m0 >> 11) * (1024ull * 2048ull);
        const int t0 = orow0 & 2047;
        #pragma unroll
        for (int n = 0; n < 4; ++n) {
            size_t e = (size_t)(ocol0 + n * 16);
            #pragma unroll
            for (int m = 0; m < 4; ++m) {
                half4 h;
                #pragma unroll
                for (int r = 0; r < 4; ++r) h[r] = (_Float16)acc[m][n][r];
                *(half4*)(C + bofs + e * 2048 + (t0 + m * 16)) = h;
            }
        }
    }
}

// ---------------------------------------------------------------------------
// In-place row softmax on S fp16 [nrows][2048]; 1 wave per row, all-register.
// ---------------------------------------------------------------------------
__global__ void softmax_rows(_Float16* __restrict__ S)
{
    const int wid  = threadIdx.x >> 6;
    const int lane = threadIdx.x & 63;
    const size_t row = (size_t)blockIdx.x * 4 + wid;
    _Float16* p = S + row * 2048;

    float v[32];
    #pragma unroll
    for (int i = 0; i < 4; ++i) {
        half8 h = *(const half8*)(p + i * 512 + lane * 8);
        #pragma unroll
        for (int j = 0; j < 8; ++j) v[i * 8 + j] = (float)h[j];
    }
    float m = -1e30f;
    #pragma unroll
    for (int t = 0; t < 32; ++t) m = fmaxf(m, v[t]);
    #pragma unroll
    for (int mask = 1; mask < 64; mask <<= 1) m = fmaxf(m, __shfl_xor(m, mask));

    float s = 0.f;
    #pragma unroll
    for (int t = 0; t < 32; ++t) { v[t] = __expf(v[t] - m); s += v[t]; }
    #pragma unroll
    for (int mask = 1; mask < 64; mask <<= 1) s += __shfl_xor(s, mask);
    const float r = 1.0f / s;

    #pragma unroll
    for (int i = 0; i < 4; ++i) {
        half8 h;
        #pragma unroll
        for (int j = 0; j < 8; ++j) h[j] = (_Float16)(v[i * 8 + j] * r);
        *(half8*)(p + i * 512 + lane * 8) = h;
    }
}

// ---------------------------------------------------------------------------
extern "C" void kernel_launch(void* const* d_in, const int* in_sizes, int n_in,
                              void* d_out, int out_size, void* d_ws, size_t ws_size,
                              hipStream_t stream)
{
    const float* x1 = (const float*)d_in[0];
    const float* x2 = (const float*)d_in[1];
    // weights in d_in[2..7]: Wq1, Wk1, Wv1, Wq2, Wk2, Wv2

    char* ws = (char*)d_ws;
    _Float16* Wt  = (_Float16*)ws;                       // 12 MB (6 x 2 MB)
    _Float16* X1h = (_Float16*)(ws + 12582912L);         // 32 MB
    _Float16* X2h = (_Float16*)(ws + 12582912L + 33554432L);
    _Float16* Q   = (_Float16*)(ws + 12582912L + 2 * 33554432L);
    _Float16* Kk  = (_Float16*)(ws + 12582912L + 3 * 33554432L);
    _Float16* Vt  = (_Float16*)(ws + 12582912L + 4 * 33554432L);
    _Float16* S   = (_Float16*)(ws + 12582912L + 5 * 33554432L);  // 64 MB

    transpose_cast6<<<dim3(16, 16, 6), 256, 0, stream>>>(
        (const float*)d_in[2], (const float*)d_in[3], (const float*)d_in[4],
        (const float*)d_in[5], (const float*)d_in[6], (const float*)d_in[7], Wt);

    cast2_f32_f16<<<dim3(2048, 2), 256, 0, stream>>>(x1, x2, X1h, X2h);

    for (int d = 0; d < 2; ++d) {
        // d==0: context_vec_2 = attn(Q=x1·Wq1, K=x2·Wk2, V=x2·Wv2) -> out[16777216:]
        // d==1: context_vec_1 = attn(Q=x2·Wq2, K=x1·Wk1, V=x1·Wv1) -> out[0:]
        const _Float16* xq  = (d == 0) ? X1h : X2h;
        const _Float16* xkv = (d == 0) ? X2h : X1h;
        const _Float16* wtq = Wt + (size_t)((d == 0) ? 0 : 3) * 1048576;
        const _Float16* wtk = Wt + (size_t)((d == 0) ? 4 : 1) * 1048576;
        const _Float16* wtv = Wt + (size_t)((d == 0) ? 5 : 2) * 1048576;
        float* outp = (float*)d_out + ((d == 0) ? 16777216L : 0L);

        gemm_bt2<0><<<dim3(8, 128, 1), 256, 0, stream>>>(xq,  wtq, Q,  1024, 1024, 1024, 1024, 0, 0, 0, 1.f);
        gemm_bt2<0><<<dim3(8, 128, 1), 256, 0, stream>>>(xkv, wtk, Kk, 1024, 1024, 1024, 1024, 0, 0, 0, 1.f);
        gemm_bt2<2><<<dim3(8, 128, 1), 256, 0, stream>>>(xkv, wtv, Vt, 1024, 1024, 0,    1024, 0, 0, 0, 1.f);

        gemm_bt2<0><<<dim3(16, 16, 8), 256, 0, stream>>>(Q, Kk, S, 1024, 1024, 2048, 1024,
                                                         2048L * 1024, 2048L * 1024, 2048L * 2048, 0.03125f);
        softmax_rows<<<4096, 256, 0, stream>>>(S);

        gemm_bt2<1><<<dim3(8, 16, 8), 256, 0, stream>>>(S, Vt, outp, 2048, 2048, 1024, 2048,
                                                        2048L * 2048, 2048L * 1024, 2048L * 1024, 1.f);
    }
}

// Round 4
// 874.732 us; speedup vs baseline: 1.3535x; 1.1229x over previous
//
#include <hip/hip_runtime.h>

typedef _Float16 half8 __attribute__((ext_vector_type(8)));
typedef _Float16 half4 __attribute__((ext_vector_type(4)));
typedef float f4 __attribute__((ext_vector_type(4)));

__device__ __forceinline__ void gload16(const void* g, void* l) {
    __builtin_amdgcn_global_load_lds(
        (const __attribute__((address_space(1))) void*)g,
        (__attribute__((address_space(3))) void*)l, 16, 0, 0);
}
#define BAR()   __builtin_amdgcn_s_barrier()
#define PRIO(x) __builtin_amdgcn_s_setprio(x)
#define LGKM0() do { asm volatile("s_waitcnt lgkmcnt(0)" ::: "memory"); \
                     __builtin_amdgcn_sched_barrier(0); } while (0)

// st_16x32 swizzle: byte offset within a [128 rows][64 K] fp16 half-tile.
// Involution: flips byte-bit5 with byte-bit9. Applied identically on the
// pre-swizzled global SOURCE (staging) and the ds_read address (rule 21).
__device__ __forceinline__ int swzb(int row, int c) {
    int a = (row << 7) + (c << 1);
    return a ^ ((a >> 4) & 32);
}

// ---------------------------------------------------------------------------
// Weight transpose+cast: W fp32 [1024(k)][1024(n)] -> Wt fp16 [1024(n)][1024(k)]
// ---------------------------------------------------------------------------
__global__ void transpose_cast6(const float* __restrict__ W0, const float* __restrict__ W1,
                                const float* __restrict__ W2, const float* __restrict__ W3,
                                const float* __restrict__ W4, const float* __restrict__ W5,
                                _Float16* __restrict__ Wt)
{
    const float* Ws[6] = {W0, W1, W2, W3, W4, W5};
    const float* W = Ws[blockIdx.z];
    _Float16* O = Wt + (size_t)blockIdx.z * (1024u * 1024u);

    __shared__ _Float16 t[64][72];
    const int tid = threadIdx.x;
    const int n0 = blockIdx.x * 64;
    const int k0 = blockIdx.y * 64;

    #pragma unroll
    for (int i = 0; i < 4; ++i) {
        int idx = tid + i * 256;
        int r = idx >> 4;
        int c4 = idx & 15;
        f4 v = *(const f4*)(W + (size_t)(k0 + r) * 1024 + n0 + c4 * 4);
        #pragma unroll
        for (int j = 0; j < 4; ++j) t[r][c4 * 4 + j] = (_Float16)v[j];
    }
    __syncthreads();
    #pragma unroll
    for (int i = 0; i < 4; ++i) {
        int idx = tid + i * 256;
        int r = idx >> 4;
        int c4 = idx & 15;
        half4 h;
        #pragma unroll
        for (int j = 0; j < 4; ++j) h[j] = t[c4 * 4 + j][r];
        *(half4*)(O + (size_t)(n0 + r) * 1024 + k0 + c4 * 4) = h;
    }
}

// ---------------------------------------------------------------------------
// Cast activations fp32 -> fp16
// ---------------------------------------------------------------------------
__global__ void cast2_f32_f16(const float* __restrict__ a, const float* __restrict__ b,
                              _Float16* __restrict__ oa, _Float16* __restrict__ ob)
{
    const float* in  = blockIdx.y ? b : a;
    _Float16*   out = blockIdx.y ? ob : oa;
    const size_t stride = (size_t)gridDim.x * 256 * 8;
    for (size_t i = ((size_t)blockIdx.x * 256 + threadIdx.x) * 8; i < 16777216ull; i += stride) {
        f4 v0 = *(const f4*)(in + i);
        f4 v1 = *(const f4*)(in + i + 4);
        half8 h;
        #pragma unroll
        for (int j = 0; j < 4; ++j) { h[j] = (_Float16)v0[j]; h[4 + j] = (_Float16)v1[j]; }
        *(half8*)(out + i) = h;
    }
}

// ---------------------------------------------------------------------------
// 8-phase 256x256 B^T GEMM (T1+T2+T3+T4+T5), fp16 inputs, fp32 accum.
// C[M,N] = A[M,K] * Bt[N,K]^T.  BK=64, 8 waves (2Mx4N), per-wave 128x64 out.
// LDS: [2 dbuf][A0,A1,B0,B1][128*64 fp16] = 128 KiB, st_16x32 swizzled.
// Per K-tile: 4 phases = 4 C-quadrants x 16 MFMA; counted vmcnt(4)/tile.
// OMODE: 0 = fp16 row-major (scaled), 1 = fp32 row-major, 2 = fp16 Vt[b][e][t]
// ---------------------------------------------------------------------------
template<int OMODE>
__global__ __launch_bounds__(512, 2)
void gemm8p(const _Float16* __restrict__ Ain, const _Float16* __restrict__ Btin,
            void* __restrict__ Cout, int lda, int ldb, int ldc, int K,
            long sAz, long sBz, long sCz, float scale)
{
    __shared__ alignas(16) _Float16 lds[2][4][8192];

    // T1: bijective XCD swizzle (all grids have nwg % 8 == 0)
    const int nwg = gridDim.x * gridDim.y * gridDim.z;
    const int lid = blockIdx.x + gridDim.x * (blockIdx.y + gridDim.y * blockIdx.z);
    const int cpx = nwg >> 3;
    const int sw  = (lid & 7) * cpx + (lid >> 3);
    const int bx  = sw % gridDim.x;
    const int tmp = sw / gridDim.x;
    const int by  = tmp % gridDim.y;
    const int bz  = tmp / gridDim.y;

    const int tid = threadIdx.x, lane = tid & 63, wid = tid >> 6;
    const int wm = wid >> 2, wn = wid & 3;       // 2 M-waves x 4 N-waves
    const int n0 = bx * 256, m0 = by * 256;

    const _Float16* A  = Ain  + (size_t)bz * sAz;
    const _Float16* Bt = Btin + (size_t)bz * sBz;
    const int KT = K >> 6;

    // stage one 128x64 half-tile (16 KB): 2 gload16/thread, linear LDS dest,
    // inverse-swizzled global source (bit9 of dest byte == lane bit5).
    auto stageHalf = [&](int buf, int reg, const _Float16* src, int ld, int row0, int kt) {
        #pragma unroll
        for (int j = 0; j < 2; ++j) {
            int D = j * 8192 + wid * 1024 + lane * 16;
            int S = D ^ (lane & 32);
            int r = S >> 7;
            int c = (S & 127) >> 1;
            gload16(src + (size_t)(row0 + r) * ld + kt * 64 + c,
                    &lds[buf][reg][j * 4096 + wid * 512]);
        }
    };

    f4 acc[8][4];
    #pragma unroll
    for (int i = 0; i < 8; ++i)
        #pragma unroll
        for (int j = 0; j < 4; ++j)
            acc[i][j] = f4{0.f, 0.f, 0.f, 0.f};

    half8 a0[4][2], a1[4][2], b[2][2];

    const int lr = lane & 15, lk = (lane >> 4) * 8;
    const int areg  = wm;            // this wave's A half-region
    const int breg  = 2 + (wn >> 1); // this wave's B half-region
    const int brow0 = (wn & 1) * 64; // N-row base within B half

    // prologue: A0(0) A1(0) B0(0) B1(0) A0(1) A1(1) -> vmcnt(4) leaves A(1) in flight
    stageHalf(0, 0, A,  lda, m0,       0);
    stageHalf(0, 1, A,  lda, m0 + 128, 0);
    stageHalf(0, 2, Bt, ldb, n0,       0);
    stageHalf(0, 3, Bt, ldb, n0 + 128, 0);
    if (KT > 1) {
        stageHalf(1, 0, A, lda, m0,       1);
        stageHalf(1, 1, A, lda, m0 + 128, 1);
    }
    asm volatile("s_waitcnt vmcnt(4)" ::: "memory");
    BAR();

    for (int t = 0; t < KT; ++t) {
        const int buf = t & 1;
        const char* LA = (const char*)lds[buf][areg];
        const char* LB = (const char*)lds[buf][breg];

        // ---- ph0: Q(0,0) ------------------------------------------------
        #pragma unroll
        for (int mf = 0; mf < 4; ++mf)
            #pragma unroll
            for (int kk = 0; kk < 2; ++kk)
                a0[mf][kk] = *(const half8*)(LA + swzb(mf * 16 + lr, kk * 32 + lk));
        #pragma unroll
        for (int nf = 0; nf < 2; ++nf)
            #pragma unroll
            for (int kk = 0; kk < 2; ++kk)
                b[nf][kk] = *(const half8*)(LB + swzb(brow0 + nf * 16 + lr, kk * 32 + lk));
        if (t + 1 < KT) stageHalf(buf ^ 1, 2, Bt, ldb, n0, t + 1);
        asm volatile("s_waitcnt lgkmcnt(8)" ::: "memory");
        BAR(); LGKM0(); PRIO(1);
        #pragma unroll
        for (int mf = 0; mf < 4; ++mf)
            #pragma unroll
            for (int nf = 0; nf < 2; ++nf)
                #pragma unroll
                for (int kk = 0; kk < 2; ++kk)
                    acc[mf][nf] = __builtin_amdgcn_mfma_f32_16x16x32_f16(a0[mf][kk], b[nf][kk], acc[mf][nf], 0, 0, 0);
        PRIO(0); BAR();

        // ---- ph1: Q(1,0) ------------------------------------------------
        #pragma unroll
        for (int mf = 0; mf < 4; ++mf)
            #pragma unroll
            for (int kk = 0; kk < 2; ++kk)
                a1[mf][kk] = *(const half8*)(LA + swzb(64 + mf * 16 + lr, kk * 32 + lk));
        if (t + 1 < KT) stageHalf(buf ^ 1, 3, Bt, ldb, n0 + 128, t + 1);
        BAR(); LGKM0(); PRIO(1);
        #pragma unroll
        for (int mf = 0; mf < 4; ++mf)
            #pragma unroll
            for (int nf = 0; nf < 2; ++nf)
                #pragma unroll
                for (int kk = 0; kk < 2; ++kk)
                    acc[4 + mf][nf] = __builtin_amdgcn_mfma_f32_16x16x32_f16(a1[mf][kk], b[nf][kk], acc[4 + mf][nf], 0, 0, 0);
        PRIO(0); BAR();

        // ---- ph2: Q(1,1) ------------------------------------------------
        #pragma unroll
        for (int nf = 0; nf < 2; ++nf)
            #pragma unroll
            for (int kk = 0; kk < 2; ++kk)
                b[nf][kk] = *(const half8*)(LB + swzb(brow0 + 32 + nf * 16 + lr, kk * 32 + lk));
        if (t + 2 < KT) stageHalf(buf, 0, A, lda, m0, t + 2);
        BAR(); LGKM0(); PRIO(1);
        #pragma unroll
        for (int mf = 0; mf < 4; ++mf)
            #pragma unroll
            for (int nf = 0; nf < 2; ++nf)
                #pragma unroll
                for (int kk = 0; kk < 2; ++kk)
                    acc[4 + mf][2 + nf] = __builtin_amdgcn_mfma_f32_16x16x32_f16(a1[mf][kk], b[nf][kk], acc[4 + mf][2 + nf], 0, 0, 0);
        PRIO(0); BAR();

        // ---- ph3: Q(0,1) ------------------------------------------------
        if (t + 2 < KT) stageHalf(buf, 1, A, lda, m0 + 128, t + 2);
        BAR(); PRIO(1);
        #pragma unroll
        for (int mf = 0; mf < 4; ++mf)
            #pragma unroll
            for (int nf = 0; nf < 2; ++nf)
                #pragma unroll
                for (int kk = 0; kk < 2; ++kk)
                    acc[mf][2 + nf] = __builtin_amdgcn_mfma_f32_16x16x32_f16(a0[mf][kk], b[nf][kk], acc[mf][2 + nf], 0, 0, 0);
        PRIO(0);
        if (t + 2 < KT) { asm volatile("s_waitcnt vmcnt(4)" ::: "memory"); }
        else            { asm volatile("s_waitcnt vmcnt(0)" ::: "memory"); }
        BAR();
    }

    // ---- epilogue -------------------------------------------------------
    if constexpr (OMODE == 0) {
        _Float16* C = (_Float16*)Cout + (size_t)bz * sCz;
        #pragma unroll
        for (int qm = 0; qm < 2; ++qm)
            #pragma unroll
            for (int mf = 0; mf < 4; ++mf)
                #pragma unroll
                for (int rr = 0; rr < 4; ++rr) {
                    size_t row = (size_t)(m0 + wm * 128 + qm * 64 + mf * 16 + (lane >> 4) * 4 + rr);
                    #pragma unroll
                    for (int qn = 0; qn < 2; ++qn)
                        #pragma unroll
                        for (int nf = 0; nf < 2; ++nf)
                            C[row * ldc + n0 + wn * 64 + qn * 32 + nf * 16 + lr] =
                                (_Float16)(acc[qm * 4 + mf][qn * 2 + nf][rr] * scale);
                }
    } else if constexpr (OMODE == 1) {
        float* C = (float*)Cout + (size_t)bz * sCz;
        #pragma unroll
        for (int qm = 0; qm < 2; ++qm)
            #pragma unroll
            for (int mf = 0; mf < 4; ++mf)
                #pragma unroll
                for (int rr = 0; rr < 4; ++rr) {
                    size_t row = (size_t)(m0 + wm * 128 + qm * 64 + mf * 16 + (lane >> 4) * 4 + rr);
                    #pragma unroll
                    for (int qn = 0; qn < 2; ++qn)
                        #pragma unroll
                        for (int nf = 0; nf < 2; ++nf)
                            C[row * ldc + n0 + wn * 64 + qn * 32 + nf * 16 + lr] =
                                acc[qm * 4 + mf][qn * 2 + nf][rr] * scale;
                }
    } else {
        // Vt[b][e][t]: b = tile batch, e = out col, t = row % 2048
        _Float16* C = (_Float16*)Cout;
        const size_t bofs = (size_t)(m0 >> 11) * (1024ull * 2048ull);
        #pragma unroll
        for (int qn = 0; qn < 2; ++qn)
            #pragma unroll
            for (int nf = 0; nf < 2; ++nf) {
                size_t e = (size_t)(n0 + wn * 64 + qn * 32 + nf * 16 + lr);
                #pragma unroll
                for (int qm = 0; qm < 2; ++qm)
                    #pragma unroll
                    for (int mf = 0; mf < 4; ++mf) {
                        int t0 = (m0 + wm * 128 + qm * 64 + mf * 16 + (lane >> 4) * 4) & 2047;
                        half4 h;
                        #pragma unroll
                        for (int rr = 0; rr < 4; ++rr) h[rr] = (_Float16)acc[qm * 4 + mf][qn * 2 + nf][rr];
                        *(half4*)(C + bofs + e * 2048 + t0) = h;
                    }
            }
    }
}

// ---------------------------------------------------------------------------
// In-place row softmax on S fp16 [nrows][2048]; 1 wave per row.
// ---------------------------------------------------------------------------
__global__ void softmax_rows(_Float16* __restrict__ S)
{
    const int wid  = threadIdx.x >> 6;
    const int lane = threadIdx.x & 63;
    const size_t row = (size_t)blockIdx.x * 4 + wid;
    _Float16* p = S + row * 2048;

    float v[32];
    #pragma unroll
    for (int i = 0; i < 4; ++i) {
        half8 h = *(const half8*)(p + i * 512 + lane * 8);
        #pragma unroll
        for (int j = 0; j < 8; ++j) v[i * 8 + j] = (float)h[j];
    }
    float m = -1e30f;
    #pragma unroll
    for (int t = 0; t < 32; ++t) m = fmaxf(m, v[t]);
    #pragma unroll
    for (int mask = 1; mask < 64; mask <<= 1) m = fmaxf(m, __shfl_xor(m, mask));

    float s = 0.f;
    #pragma unroll
    for (int t = 0; t < 32; ++t) { v[t] = __expf(v[t] - m); s += v[t]; }
    #pragma unroll
    for (int mask = 1; mask < 64; mask <<= 1) s += __shfl_xor(s, mask);
    const float r = 1.0f / s;

    #pragma unroll
    for (int i = 0; i < 4; ++i) {
        half8 h;
        #pragma unroll
        for (int j = 0; j < 8; ++j) h[j] = (_Float16)(v[i * 8 + j] * r);
        *(half8*)(p + i * 512 + lane * 8) = h;
    }
}

// ---------------------------------------------------------------------------
extern "C" void kernel_launch(void* const* d_in, const int* in_sizes, int n_in,
                              void* d_out, int out_size, void* d_ws, size_t ws_size,
                              hipStream_t stream)
{
    const float* x1 = (const float*)d_in[0];
    const float* x2 = (const float*)d_in[1];
    // weights in d_in[2..7]: Wq1, Wk1, Wv1, Wq2, Wk2, Wv2

    char* ws = (char*)d_ws;
    _Float16* Wt  = (_Float16*)ws;                       // 12 MB (6 x 2 MB)
    _Float16* X1h = (_Float16*)(ws + 12582912L);         // 32 MB
    _Float16* X2h = (_Float16*)(ws + 12582912L + 33554432L);
    _Float16* Q   = (_Float16*)(ws + 12582912L + 2 * 33554432L);
    _Float16* Kk  = (_Float16*)(ws + 12582912L + 3 * 33554432L);
    _Float16* Vt  = (_Float16*)(ws + 12582912L + 4 * 33554432L);
    _Float16* S   = (_Float16*)(ws + 12582912L + 5 * 33554432L);  // 64 MB

    transpose_cast6<<<dim3(16, 16, 6), 256, 0, stream>>>(
        (const float*)d_in[2], (const float*)d_in[3], (const float*)d_in[4],
        (const float*)d_in[5], (const float*)d_in[6], (const float*)d_in[7], Wt);

    cast2_f32_f16<<<dim3(2048, 2), 256, 0, stream>>>(x1, x2, X1h, X2h);

    for (int d = 0; d < 2; ++d) {
        // d==0: context_vec_2 = attn(Q=x1·Wq1, K=x2·Wk2, V=x2·Wv2) -> out[16777216:]
        // d==1: context_vec_1 = attn(Q=x2·Wq2, K=x1·Wk1, V=x1·Wv1) -> out[0:]
        const _Float16* xq  = (d == 0) ? X1h : X2h;
        const _Float16* xkv = (d == 0) ? X2h : X1h;
        const _Float16* wtq = Wt + (size_t)((d == 0) ? 0 : 3) * 1048576;
        const _Float16* wtk = Wt + (size_t)((d == 0) ? 4 : 1) * 1048576;
        const _Float16* wtv = Wt + (size_t)((d == 0) ? 5 : 2) * 1048576;
        float* outp = (float*)d_out + ((d == 0) ? 16777216L : 0L);

        gemm8p<0><<<dim3(4, 64, 1), 512, 0, stream>>>(xq,  wtq, Q,  1024, 1024, 1024, 1024, 0, 0, 0, 1.f);
        gemm8p<0><<<dim3(4, 64, 1), 512, 0, stream>>>(xkv, wtk, Kk, 1024, 1024, 1024, 1024, 0, 0, 0, 1.f);
        gemm8p<2><<<dim3(4, 64, 1), 512, 0, stream>>>(xkv, wtv, Vt, 1024, 1024, 0,    1024, 0, 0, 0, 1.f);

        gemm8p<0><<<dim3(8, 8, 8), 512, 0, stream>>>(Q, Kk, S, 1024, 1024, 2048, 1024,
                                                     2048L * 1024, 2048L * 1024, 2048L * 2048, 0.03125f);
        softmax_rows<<<4096, 256, 0, stream>>>(S);

        gemm8p<1><<<dim3(4, 8, 8), 512, 0, stream>>>(S, Vt, outp, 2048, 2048, 1024, 2048,
                                                     2048L * 2048, 2048L * 1024, 2048L * 1024, 1.f);
    }
}

// Round 5
// 794.126 us; speedup vs baseline: 1.4908x; 1.1015x over previous
//
#include <hip/hip_runtime.h>

typedef _Float16 half8 __attribute__((ext_vector_type(8)));
typedef _Float16 half4 __attribute__((ext_vector_type(4)));
typedef float f4 __attribute__((ext_vector_type(4)));

__device__ __forceinline__ void gload16(const void* g, void* l) {
    __builtin_amdgcn_global_load_lds(
        (const __attribute__((address_space(1))) void*)g,
        (__attribute__((address_space(3))) void*)l, 16, 0, 0);
}
#define BAR()   __builtin_amdgcn_s_barrier()
#define PRIO(x) __builtin_amdgcn_s_setprio(x)
#define LGKM0() do { asm volatile("s_waitcnt lgkmcnt(0)" ::: "memory"); \
                     __builtin_amdgcn_sched_barrier(0); } while (0)

// Bank-conflict-free swizzle for [128 rows][128 bytes] fp16 half-tiles read
// as ds_read_b128 by 16-consecutive-row lane groups at fixed column:
//   byte_col ^= ((row & 7) << 4)
// Rows 0..7 cover all 8 16B slots (all 32 banks); rows 8..15 alias 2-way (free).
// Involution; applied to pre-swizzled global SOURCE + ds_read addr (rule 21).
__device__ __forceinline__ int swzb(int row, int c_half) {
    return (row << 7) + ((c_half << 1) ^ ((row & 7) << 4));
}

// ---------------------------------------------------------------------------
// Weight transpose+cast: W fp32 [1024(k)][1024(n)] -> Wt fp16 [1024(n)][1024(k)]
// ---------------------------------------------------------------------------
__global__ void transpose_cast6(const float* __restrict__ W0, const float* __restrict__ W1,
                                const float* __restrict__ W2, const float* __restrict__ W3,
                                const float* __restrict__ W4, const float* __restrict__ W5,
                                _Float16* __restrict__ Wt)
{
    const float* Ws[6] = {W0, W1, W2, W3, W4, W5};
    const float* W = Ws[blockIdx.z];
    _Float16* O = Wt + (size_t)blockIdx.z * (1024u * 1024u);

    __shared__ _Float16 t[64][72];
    const int tid = threadIdx.x;
    const int n0 = blockIdx.x * 64;
    const int k0 = blockIdx.y * 64;

    #pragma unroll
    for (int i = 0; i < 4; ++i) {
        int idx = tid + i * 256;
        int r = idx >> 4;
        int c4 = idx & 15;
        f4 v = *(const f4*)(W + (size_t)(k0 + r) * 1024 + n0 + c4 * 4);
        #pragma unroll
        for (int j = 0; j < 4; ++j) t[r][c4 * 4 + j] = (_Float16)v[j];
    }
    __syncthreads();
    #pragma unroll
    for (int i = 0; i < 4; ++i) {
        int idx = tid + i * 256;
        int r = idx >> 4;
        int c4 = idx & 15;
        half4 h;
        #pragma unroll
        for (int j = 0; j < 4; ++j) h[j] = t[c4 * 4 + j][r];
        *(half4*)(O + (size_t)(n0 + r) * 1024 + k0 + c4 * 4) = h;
    }
}

// ---------------------------------------------------------------------------
// Cast activations fp32 -> fp16
// ---------------------------------------------------------------------------
__global__ void cast2_f32_f16(const float* __restrict__ a, const float* __restrict__ b,
                              _Float16* __restrict__ oa, _Float16* __restrict__ ob)
{
    const float* in  = blockIdx.y ? b : a;
    _Float16*   out = blockIdx.y ? ob : oa;
    const size_t stride = (size_t)gridDim.x * 256 * 8;
    for (size_t i = ((size_t)blockIdx.x * 256 + threadIdx.x) * 8; i < 16777216ull; i += stride) {
        f4 v0 = *(const f4*)(in + i);
        f4 v1 = *(const f4*)(in + i + 4);
        half8 h;
        #pragma unroll
        for (int j = 0; j < 4; ++j) { h[j] = (_Float16)v0[j]; h[4 + j] = (_Float16)v1[j]; }
        *(half8*)(out + i) = h;
    }
}

// ---------------------------------------------------------------------------
// 8-phase 256x256 B^T GEMM (T1+T2+T3+T4+T5), fp16 inputs, fp32 accum.
// C[M,N] = A[M,K] * Bt[N,K]^T.  BK=64, 8 waves (2Mx4N), per-wave 128x64 out.
// LDS: [2 dbuf][A0,A1,B0,B1][128*64 fp16] = 128 KiB, swizzled per swzb().
// Per K-tile: 4 phases = 4 C-quadrants x 16 MFMA; counted vmcnt(4)/tile.
// OMODE: 0 = fp16 row-major (scaled), 1 = fp32 row-major, 2 = fp16 Vt[b][e][t]
// ---------------------------------------------------------------------------
template<int OMODE>
__global__ __launch_bounds__(512, 2)
void gemm8p(const _Float16* __restrict__ Ain, const _Float16* __restrict__ Btin,
            void* __restrict__ Cout, int lda, int ldb, int ldc, int K,
            long sAz, long sBz, long sCz, float scale)
{
    __shared__ alignas(16) _Float16 lds[2][4][8192];

    // T1: bijective XCD swizzle (all grids have nwg % 8 == 0)
    const int nwg = gridDim.x * gridDim.y * gridDim.z;
    const int lid = blockIdx.x + gridDim.x * (blockIdx.y + gridDim.y * blockIdx.z);
    const int cpx = nwg >> 3;
    const int sw  = (lid & 7) * cpx + (lid >> 3);
    const int bx  = sw % gridDim.x;
    const int tmp = sw / gridDim.x;
    const int by  = tmp % gridDim.y;
    const int bz  = tmp / gridDim.y;

    const int tid = threadIdx.x, lane = tid & 63, wid = tid >> 6;
    const int wm = wid >> 2, wn = wid & 3;       // 2 M-waves x 4 N-waves
    const int n0 = bx * 256, m0 = by * 256;

    const _Float16* A  = Ain  + (size_t)bz * sAz;
    const _Float16* Bt = Btin + (size_t)bz * sBz;
    const int KT = K >> 6;

    // stage one 128x64 half-tile (16 KB): 2 gload16/thread, linear LDS dest,
    // inverse-swizzled global source (same involution as swzb).
    auto stageHalf = [&](int buf, int reg, const _Float16* src, int ld, int row0, int kt) {
        #pragma unroll
        for (int j = 0; j < 2; ++j) {
            int D = j * 8192 + wid * 1024 + lane * 16;   // linear dest byte
            int r = D >> 7;
            int c = (D & 127) ^ ((r & 7) << 4);          // source byte col
            gload16(src + (size_t)(row0 + r) * ld + kt * 64 + (c >> 1),
                    &lds[buf][reg][j * 4096 + wid * 512]);
        }
    };

    f4 acc[8][4];
    #pragma unroll
    for (int i = 0; i < 8; ++i)
        #pragma unroll
        for (int j = 0; j < 4; ++j)
            acc[i][j] = f4{0.f, 0.f, 0.f, 0.f};

    half8 a0[4][2], a1[4][2], b[2][2];

    const int lr = lane & 15, lk = (lane >> 4) * 8;
    const int areg  = wm;            // this wave's A half-region
    const int breg  = 2 + (wn >> 1); // this wave's B half-region
    const int brow0 = (wn & 1) * 64; // N-row base within B half

    // prologue: A0(0) A1(0) B0(0) B1(0) A0(1) A1(1) -> vmcnt(4) leaves A(1) in flight
    stageHalf(0, 0, A,  lda, m0,       0);
    stageHalf(0, 1, A,  lda, m0 + 128, 0);
    stageHalf(0, 2, Bt, ldb, n0,       0);
    stageHalf(0, 3, Bt, ldb, n0 + 128, 0);
    if (KT > 1) {
        stageHalf(1, 0, A, lda, m0,       1);
        stageHalf(1, 1, A, lda, m0 + 128, 1);
    }
    asm volatile("s_waitcnt vmcnt(4)" ::: "memory");
    BAR();

    for (int t = 0; t < KT; ++t) {
        const int buf = t & 1;
        const char* LA = (const char*)lds[buf][areg];
        const char* LB = (const char*)lds[buf][breg];

        // ---- ph0: Q(0,0) ------------------------------------------------
        #pragma unroll
        for (int mf = 0; mf < 4; ++mf)
            #pragma unroll
            for (int kk = 0; kk < 2; ++kk)
                a0[mf][kk] = *(const half8*)(LA + swzb(mf * 16 + lr, kk * 32 + lk));
        #pragma unroll
        for (int nf = 0; nf < 2; ++nf)
            #pragma unroll
            for (int kk = 0; kk < 2; ++kk)
                b[nf][kk] = *(const half8*)(LB + swzb(brow0 + nf * 16 + lr, kk * 32 + lk));
        if (t + 1 < KT) stageHalf(buf ^ 1, 2, Bt, ldb, n0, t + 1);
        asm volatile("s_waitcnt lgkmcnt(8)" ::: "memory");
        BAR(); LGKM0(); PRIO(1);
        #pragma unroll
        for (int mf = 0; mf < 4; ++mf)
            #pragma unroll
            for (int nf = 0; nf < 2; ++nf)
                #pragma unroll
                for (int kk = 0; kk < 2; ++kk)
                    acc[mf][nf] = __builtin_amdgcn_mfma_f32_16x16x32_f16(a0[mf][kk], b[nf][kk], acc[mf][nf], 0, 0, 0);
        PRIO(0); BAR();

        // ---- ph1: Q(1,0) ------------------------------------------------
        #pragma unroll
        for (int mf = 0; mf < 4; ++mf)
            #pragma unroll
            for (int kk = 0; kk < 2; ++kk)
                a1[mf][kk] = *(const half8*)(LA + swzb(64 + mf * 16 + lr, kk * 32 + lk));
        if (t + 1 < KT) stageHalf(buf ^ 1, 3, Bt, ldb, n0 + 128, t + 1);
        BAR(); LGKM0(); PRIO(1);
        #pragma unroll
        for (int mf = 0; mf < 4; ++mf)
            #pragma unroll
            for (int nf = 0; nf < 2; ++nf)
                #pragma unroll
                for (int kk = 0; kk < 2; ++kk)
                    acc[4 + mf][nf] = __builtin_amdgcn_mfma_f32_16x16x32_f16(a1[mf][kk], b[nf][kk], acc[4 + mf][nf], 0, 0, 0);
        PRIO(0); BAR();

        // ---- ph2: Q(1,1) ------------------------------------------------
        #pragma unroll
        for (int nf = 0; nf < 2; ++nf)
            #pragma unroll
            for (int kk = 0; kk < 2; ++kk)
                b[nf][kk] = *(const half8*)(LB + swzb(brow0 + 32 + nf * 16 + lr, kk * 32 + lk));
        if (t + 2 < KT) stageHalf(buf, 0, A, lda, m0, t + 2);
        BAR(); LGKM0(); PRIO(1);
        #pragma unroll
        for (int mf = 0; mf < 4; ++mf)
            #pragma unroll
            for (int nf = 0; nf < 2; ++nf)
                #pragma unroll
                for (int kk = 0; kk < 2; ++kk)
                    acc[4 + mf][2 + nf] = __builtin_amdgcn_mfma_f32_16x16x32_f16(a1[mf][kk], b[nf][kk], acc[4 + mf][2 + nf], 0, 0, 0);
        PRIO(0); BAR();

        // ---- ph3: Q(0,1) ------------------------------------------------
        if (t + 2 < KT) stageHalf(buf, 1, A, lda, m0 + 128, t + 2);
        BAR(); PRIO(1);
        #pragma unroll
        for (int mf = 0; mf < 4; ++mf)
            #pragma unroll
            for (int nf = 0; nf < 2; ++nf)
                #pragma unroll
                for (int kk = 0; kk < 2; ++kk)
                    acc[mf][2 + nf] = __builtin_amdgcn_mfma_f32_16x16x32_f16(a0[mf][kk], b[nf][kk], acc[mf][2 + nf], 0, 0, 0);
        PRIO(0);
        if (t + 2 < KT) { asm volatile("s_waitcnt vmcnt(4)" ::: "memory"); }
        else            { asm volatile("s_waitcnt vmcnt(0)" ::: "memory"); }
        BAR();
    }

    // ---- epilogue -------------------------------------------------------
    if constexpr (OMODE == 0) {
        _Float16* C = (_Float16*)Cout + (size_t)bz * sCz;
        #pragma unroll
        for (int qm = 0; qm < 2; ++qm)
            #pragma unroll
            for (int mf = 0; mf < 4; ++mf)
                #pragma unroll
                for (int rr = 0; rr < 4; ++rr) {
                    size_t row = (size_t)(m0 + wm * 128 + qm * 64 + mf * 16 + (lane >> 4) * 4 + rr);
                    #pragma unroll
                    for (int qn = 0; qn < 2; ++qn)
                        #pragma unroll
                        for (int nf = 0; nf < 2; ++nf)
                            C[row * ldc + n0 + wn * 64 + qn * 32 + nf * 16 + lr] =
                                (_Float16)(acc[qm * 4 + mf][qn * 2 + nf][rr] * scale);
                }
    } else if constexpr (OMODE == 1) {
        float* C = (float*)Cout + (size_t)bz * sCz;
        #pragma unroll
        for (int qm = 0; qm < 2; ++qm)
            #pragma unroll
            for (int mf = 0; mf < 4; ++mf)
                #pragma unroll
                for (int rr = 0; rr < 4; ++rr) {
                    size_t row = (size_t)(m0 + wm * 128 + qm * 64 + mf * 16 + (lane >> 4) * 4 + rr);
                    #pragma unroll
                    for (int qn = 0; qn < 2; ++qn)
                        #pragma unroll
                        for (int nf = 0; nf < 2; ++nf)
                            C[row * ldc + n0 + wn * 64 + qn * 32 + nf * 16 + lr] =
                                acc[qm * 4 + mf][qn * 2 + nf][rr] * scale;
                }
    } else {
        // Vt[b][e][t]: b = tile batch, e = out col, t = row % 2048
        _Float16* C = (_Float16*)Cout;
        const size_t bofs = (size_t)(m0 >> 11) * (1024ull * 2048ull);
        #pragma unroll
        for (int qn = 0; qn < 2; ++qn)
            #pragma unroll
            for (int nf = 0; nf < 2; ++nf) {
                size_t e = (size_t)(n0 + wn * 64 + qn * 32 + nf * 16 + lr);
                #pragma unroll
                for (int qm = 0; qm < 2; ++qm)
                    #pragma unroll
                    for (int mf = 0; mf < 4; ++mf) {
                        int t0 = (m0 + wm * 128 + qm * 64 + mf * 16 + (lane >> 4) * 4) & 2047;
                        half4 h;
                        #pragma unroll
                        for (int rr = 0; rr < 4; ++rr) h[rr] = (_Float16)acc[qm * 4 + mf][qn * 2 + nf][rr];
                        *(half4*)(C + bofs + e * 2048 + t0) = h;
                    }
            }
    }
}

// ---------------------------------------------------------------------------
// In-place row softmax on S fp16 [nrows][2048]; 1 wave per row.
// ---------------------------------------------------------------------------
__global__ void softmax_rows(_Float16* __restrict__ S)
{
    const int wid  = threadIdx.x >> 6;
    const int lane = threadIdx.x & 63;
    const size_t row = (size_t)blockIdx.x * 4 + wid;
    _Float16* p = S + row * 2048;

    float v[32];
    #pragma unroll
    for (int i = 0; i < 4; ++i) {
        half8 h = *(const half8*)(p + i * 512 + lane * 8);
        #pragma unroll
        for (int j = 0; j < 8; ++j) v[i * 8 + j] = (float)h[j];
    }
    float m = -1e30f;
    #pragma unroll
    for (int t = 0; t < 32; ++t) m = fmaxf(m, v[t]);
    #pragma unroll
    for (int mask = 1; mask < 64; mask <<= 1) m = fmaxf(m, __shfl_xor(m, mask));

    float s = 0.f;
    #pragma unroll
    for (int t = 0; t < 32; ++t) { v[t] = __expf(v[t] - m); s += v[t]; }
    #pragma unroll
    for (int mask = 1; mask < 64; mask <<= 1) s += __shfl_xor(s, mask);
    const float r = 1.0f / s;

    #pragma unroll
    for (int i = 0; i < 4; ++i) {
        half8 h;
        #pragma unroll
        for (int j = 0; j < 8; ++j) h[j] = (_Float16)(v[i * 8 + j] * r);
        *(half8*)(p + i * 512 + lane * 8) = h;
    }
}

// ---------------------------------------------------------------------------
extern "C" void kernel_launch(void* const* d_in, const int* in_sizes, int n_in,
                              void* d_out, int out_size, void* d_ws, size_t ws_size,
                              hipStream_t stream)
{
    const float* x1 = (const float*)d_in[0];
    const float* x2 = (const float*)d_in[1];
    // weights in d_in[2..7]: Wq1, Wk1, Wv1, Wq2, Wk2, Wv2

    char* ws = (char*)d_ws;
    _Float16* Wt  = (_Float16*)ws;                       // 12 MB (6 x 2 MB)
    _Float16* X1h = (_Float16*)(ws + 12582912L);         // 32 MB
    _Float16* X2h = (_Float16*)(ws + 12582912L + 33554432L);
    _Float16* Q   = (_Float16*)(ws + 12582912L + 2 * 33554432L);
    _Float16* Kk  = (_Float16*)(ws + 12582912L + 3 * 33554432L);
    _Float16* Vt  = (_Float16*)(ws + 12582912L + 4 * 33554432L);
    _Float16* S   = (_Float16*)(ws + 12582912L + 5 * 33554432L);  // 64 MB

    transpose_cast6<<<dim3(16, 16, 6), 256, 0, stream>>>(
        (const float*)d_in[2], (const float*)d_in[3], (const float*)d_in[4],
        (const float*)d_in[5], (const float*)d_in[6], (const float*)d_in[7], Wt);

    cast2_f32_f16<<<dim3(2048, 2), 256, 0, stream>>>(x1, x2, X1h, X2h);

    for (int d = 0; d < 2; ++d) {
        // d==0: context_vec_2 = attn(Q=x1·Wq1, K=x2·Wk2, V=x2·Wv2) -> out[16777216:]
        // d==1: context_vec_1 = attn(Q=x2·Wq2, K=x1·Wk1, V=x1·Wv1) -> out[0:]
        const _Float16* xq  = (d == 0) ? X1h : X2h;
        const _Float16* xkv = (d == 0) ? X2h : X1h;
        const _Float16* wtq = Wt + (size_t)((d == 0) ? 0 : 3) * 1048576;
        const _Float16* wtk = Wt + (size_t)((d == 0) ? 4 : 1) * 1048576;
        const _Float16* wtv = Wt + (size_t)((d == 0) ? 5 : 2) * 1048576;
        float* outp = (float*)d_out + ((d == 0) ? 16777216L : 0L);

        gemm8p<0><<<dim3(4, 64, 1), 512, 0, stream>>>(xq,  wtq, Q,  1024, 1024, 1024, 1024, 0, 0, 0, 1.f);
        gemm8p<0><<<dim3(4, 64, 1), 512, 0, stream>>>(xkv, wtk, Kk, 1024, 1024, 1024, 1024, 0, 0, 0, 1.f);
        gemm8p<2><<<dim3(4, 64, 1), 512, 0, stream>>>(xkv, wtv, Vt, 1024, 1024, 0,    1024, 0, 0, 0, 1.f);

        gemm8p<0><<<dim3(8, 8, 8), 512, 0, stream>>>(Q, Kk, S, 1024, 1024, 2048, 1024,
                                                     2048L * 1024, 2048L * 1024, 2048L * 2048, 0.03125f);
        softmax_rows<<<4096, 256, 0, stream>>>(S);

        gemm8p<1><<<dim3(4, 8, 8), 512, 0, stream>>>(S, Vt, outp, 2048, 2048, 1024, 2048,
                                                     2048L * 2048, 2048L * 1024, 2048L * 1024, 1.f);
    }
}

// Round 7
// 782.783 us; speedup vs baseline: 1.5124x; 1.0145x over previous
//
#include <hip/hip_runtime.h>

typedef _Float16 half8 __attribute__((ext_vector_type(8)));
typedef _Float16 half4 __attribute__((ext_vector_type(4)));
typedef float f4 __attribute__((ext_vector_type(4)));

__device__ __forceinline__ void gload16(const void* g, void* l) {
    __builtin_amdgcn_global_load_lds(
        (const __attribute__((address_space(1))) void*)g,
        (__attribute__((address_space(3))) void*)l, 16, 0, 0);
}
#define BAR()   __builtin_amdgcn_s_barrier()
#define PRIO(x) __builtin_amdgcn_s_setprio(x)
// counted waits; sched_barrier stops hipcc hoisting reg-only MFMA past the asm (rule 18)
#define LGKMW(n) do { asm volatile("s_waitcnt lgkmcnt(" #n ")" ::: "memory"); \
                      __builtin_amdgcn_sched_barrier(0); } while (0)
#define VMW(n)   do { asm volatile("s_waitcnt vmcnt(" #n ")" ::: "memory"); \
                      __builtin_amdgcn_sched_barrier(0); } while (0)

// Bank-conflict-free swizzle for [128 rows][128 bytes] fp16 half-tiles read
// as ds_read_b128 by 16-consecutive-row lane groups at fixed column:
//   byte_col ^= ((row & 7) << 4)   (verified: SQ_LDS_BANK_CONFLICT -> 0)
__device__ __forceinline__ int swzb(int row, int c_half) {
    return (row << 7) + ((c_half << 1) ^ ((row & 7) << 4));
}

// ---------------------------------------------------------------------------
// Weight transpose+cast: W fp32 [1024(k)][1024(n)] -> Wt fp16 [1024(n)][1024(k)]
// ---------------------------------------------------------------------------
__global__ void transpose_cast6(const float* __restrict__ W0, const float* __restrict__ W1,
                                const float* __restrict__ W2, const float* __restrict__ W3,
                                const float* __restrict__ W4, const float* __restrict__ W5,
                                _Float16* __restrict__ Wt)
{
    const float* Ws[6] = {W0, W1, W2, W3, W4, W5};
    const float* W = Ws[blockIdx.z];
    _Float16* O = Wt + (size_t)blockIdx.z * (1024u * 1024u);

    __shared__ _Float16 t[64][72];
    const int tid = threadIdx.x;
    const int n0 = blockIdx.x * 64;
    const int k0 = blockIdx.y * 64;

    #pragma unroll
    for (int i = 0; i < 4; ++i) {
        int idx = tid + i * 256;
        int r = idx >> 4;
        int c4 = idx & 15;
        f4 v = *(const f4*)(W + (size_t)(k0 + r) * 1024 + n0 + c4 * 4);
        #pragma unroll
        for (int j = 0; j < 4; ++j) t[r][c4 * 4 + j] = (_Float16)v[j];
    }
    __syncthreads();
    #pragma unroll
    for (int i = 0; i < 4; ++i) {
        int idx = tid + i * 256;
        int r = idx >> 4;
        int c4 = idx & 15;
        half4 h;
        #pragma unroll
        for (int j = 0; j < 4; ++j) h[j] = t[c4 * 4 + j][r];
        *(half4*)(O + (size_t)(n0 + r) * 1024 + k0 + c4 * 4) = h;
    }
}

// ---------------------------------------------------------------------------
// Cast activations fp32 -> fp16
// ---------------------------------------------------------------------------
__global__ void cast2_f32_f16(const float* __restrict__ a, const float* __restrict__ b,
                              _Float16* __restrict__ oa, _Float16* __restrict__ ob)
{
    const float* in  = blockIdx.y ? b : a;
    _Float16*   out = blockIdx.y ? ob : oa;
    const size_t stride = (size_t)gridDim.x * 256 * 8;
    for (size_t i = ((size_t)blockIdx.x * 256 + threadIdx.x) * 8; i < 16777216ull; i += stride) {
        f4 v0 = *(const f4*)(in + i);
        f4 v1 = *(const f4*)(in + i + 4);
        half8 h;
        #pragma unroll
        for (int j = 0; j < 4; ++j) { h[j] = (_Float16)v0[j]; h[4 + j] = (_Float16)v1[j]; }
        *(half8*)(out + i) = h;
    }
}

// ---------------------------------------------------------------------------
// Pipelined 256x256 B^T GEMM (T1+T2+T4+T5), fp16 inputs, fp32 accum.
// C[M,N] = A[M,K] * Bt[N,K]^T.  BK=64, 8 waves (2Mx4N), per-wave 128x64 out.
// LDS: [2 dbuf][A0,A1,B0,B1][128*64 fp16] = 128 KiB, swizzled per swzb().
// Schedule per K-tile (2 barriers, all waits counted, ds_reads issued one
// MFMA-cluster ahead of their consumption):
//   pre: R_a0,R_b01 issued across previous barrier
//   P0: stage B0(t+1); lgkm(0); M00; issue R_a1
//   P1: stage B1(t+1); lgkm(0); M10; issue R_b23; BAR (A-read fence)
//   P2: stage A0(t+2); lgkm(0); M11
//   P3: stage A1(t+2); M01; vmcnt(4); BAR; issue R_a0,R_b01 (buf^1)
// OMODE: 0 = fp16 row-major (scaled), 1 = fp32 row-major, 2 = fp16 Vt[b][e][t]
// ---------------------------------------------------------------------------
template<int OMODE>
__global__ __launch_bounds__(512, 2)
void gemm8p(const _Float16* __restrict__ Ain, const _Float16* __restrict__ Btin,
            void* __restrict__ Cout, int lda, int ldb, int ldc, int K,
            long sAz, long sBz, long sCz, float scale)
{
    __shared__ alignas(16) _Float16 lds[2][4][8192];

    // T1: bijective XCD swizzle (all grids have nwg % 8 == 0)
    const int nwg = gridDim.x * gridDim.y * gridDim.z;
    const int lid = blockIdx.x + gridDim.x * (blockIdx.y + gridDim.y * blockIdx.z);
    const int cpx = nwg >> 3;
    const int sw  = (lid & 7) * cpx + (lid >> 3);
    const int bx  = sw % gridDim.x;
    const int tmp = sw / gridDim.x;
    const int by  = tmp % gridDim.y;
    const int bz  = tmp / gridDim.y;

    const int tid = threadIdx.x, lane = tid & 63, wid = tid >> 6;
    const int wm = wid >> 2, wn = wid & 3;       // 2 M-waves x 4 N-waves
    const int n0 = bx * 256, m0 = by * 256;

    const _Float16* A  = Ain  + (size_t)bz * sAz;
    const _Float16* Bt = Btin + (size_t)bz * sBz;
    const int KT = K >> 6;

    // stage one 128x64 half-tile (16 KB): 2 gload16/thread, linear LDS dest,
    // inverse-swizzled global source (same involution as swzb).
    auto stageHalf = [&](int buf, int reg, const _Float16* src, int ld, int row0, int kt) {
        #pragma unroll
        for (int j = 0; j < 2; ++j) {
            int D = j * 8192 + wid * 1024 + lane * 16;   // linear dest byte
            int r = D >> 7;
            int c = (D & 127) ^ ((r & 7) << 4);          // source byte col
            gload16(src + (size_t)(row0 + r) * ld + kt * 64 + (c >> 1),
                    &lds[buf][reg][j * 4096 + wid * 512]);
        }
    };

    f4 acc[8][4];
    #pragma unroll
    for (int i = 0; i < 8; ++i)
        #pragma unroll
        for (int j = 0; j < 4; ++j)
            acc[i][j] = f4{0.f, 0.f, 0.f, 0.f};

    half8 a0[4][2], a1[4][2], b[2][2];

    const int lr = lane & 15, lk = (lane >> 4) * 8;
    const int areg  = wm;            // this wave's A half-region
    const int breg  = 2 + (wn >> 1); // this wave's B half-region
    const int brow0 = (wn & 1) * 64; // N-row base within B half

    auto readA0 = [&](int b_) {
        const char* L = (const char*)lds[b_][areg];
        #pragma unroll
        for (int mf = 0; mf < 4; ++mf)
            #pragma unroll
            for (int kk = 0; kk < 2; ++kk)
                a0[mf][kk] = *(const half8*)(L + swzb(mf * 16 + lr, kk * 32 + lk));
    };
    auto readA1 = [&](int b_) {
        const char* L = (const char*)lds[b_][areg];
        #pragma unroll
        for (int mf = 0; mf < 4; ++mf)
            #pragma unroll
            for (int kk = 0; kk < 2; ++kk)
                a1[mf][kk] = *(const half8*)(L + swzb(64 + mf * 16 + lr, kk * 32 + lk));
    };
    auto readB01 = [&](int b_) {
        const char* L = (const char*)lds[b_][breg];
        #pragma unroll
        for (int nf = 0; nf < 2; ++nf)
            #pragma unroll
            for (int kk = 0; kk < 2; ++kk)
                b[nf][kk] = *(const half8*)(L + swzb(brow0 + nf * 16 + lr, kk * 32 + lk));
    };
    auto readB23 = [&](int b_) {
        const char* L = (const char*)lds[b_][breg];
        #pragma unroll
        for (int nf = 0; nf < 2; ++nf)
            #pragma unroll
            for (int kk = 0; kk < 2; ++kk)
                b[nf][kk] = *(const half8*)(L + swzb(brow0 + 32 + nf * 16 + lr, kk * 32 + lk));
    };
    auto mfmaA0 = [&](int bj) {   // a0 x b -> acc[0..3][bj..bj+1]
        #pragma unroll
        for (int mf = 0; mf < 4; ++mf)
            #pragma unroll
            for (int nf = 0; nf < 2; ++nf)
                #pragma unroll
                for (int kk = 0; kk < 2; ++kk)
                    acc[mf][bj + nf] = __builtin_amdgcn_mfma_f32_16x16x32_f16(a0[mf][kk], b[nf][kk], acc[mf][bj + nf], 0, 0, 0);
    };
    auto mfmaA1 = [&](int bj) {   // a1 x b -> acc[4..7][bj..bj+1]
        #pragma unroll
        for (int mf = 0; mf < 4; ++mf)
            #pragma unroll
            for (int nf = 0; nf < 2; ++nf)
                #pragma unroll
                for (int kk = 0; kk < 2; ++kk)
                    acc[4 + mf][bj + nf] = __builtin_amdgcn_mfma_f32_16x16x32_f16(a1[mf][kk], b[nf][kk], acc[4 + mf][bj + nf], 0, 0, 0);
    };

    // prologue: buf0 all 4 halves + buf1 A halves; vmcnt(4) drains buf0
    stageHalf(0, 0, A,  lda, m0,       0);
    stageHalf(0, 1, A,  lda, m0 + 128, 0);
    stageHalf(0, 2, Bt, ldb, n0,       0);
    stageHalf(0, 3, Bt, ldb, n0 + 128, 0);
    if (KT > 1) {
        stageHalf(1, 0, A, lda, m0,       1);
        stageHalf(1, 1, A, lda, m0 + 128, 1);
    }
    VMW(4);
    BAR();
    readA0(0);
    readB01(0);

    for (int t = 0; t < KT; ++t) {
        const int buf = t & 1;

        // ---- P0: M00 ----------------------------------------------------
        if (t + 1 < KT) stageHalf(buf ^ 1, 2, Bt, ldb, n0, t + 1);
        LGKMW(0); PRIO(1);
        mfmaA0(0);
        PRIO(0);
        readA1(buf);

        // ---- P1: M10 ----------------------------------------------------
        if (t + 1 < KT) stageHalf(buf ^ 1, 3, Bt, ldb, n0 + 128, t + 1);
        LGKMW(0); PRIO(1);
        mfmaA1(0);
        PRIO(0);
        readB23(buf);
        BAR();   // all waves' A-region reads complete -> A stages below are safe

        // ---- P2: M11 ----------------------------------------------------
        if (t + 2 < KT) stageHalf(buf, 0, A, lda, m0, t + 2);
        LGKMW(0); PRIO(1);
        mfmaA1(2);
        PRIO(0);

        // ---- P3: M01 ----------------------------------------------------
        if (t + 2 < KT) stageHalf(buf, 1, A, lda, m0 + 128, t + 2);
        PRIO(1);
        mfmaA0(2);
        PRIO(0);
        if (t + 2 < KT) { VMW(4); } else { VMW(0); }
        BAR();   // buf^1's A(t+1), B(t+1) landed and visible
        if (t + 1 < KT) { readA0(buf ^ 1); readB01(buf ^ 1); }
    }

    // ---- epilogue -------------------------------------------------------
    if constexpr (OMODE == 0) {
        _Float16* C = (_Float16*)Cout + (size_t)bz * sCz;
        #pragma unroll
        for (int qm = 0; qm < 2; ++qm)
            #pragma unroll
            for (int mf = 0; mf < 4; ++mf)
                #pragma unroll
                for (int rr = 0; rr < 4; ++rr) {
                    size_t row = (size_t)(m0 + wm * 128 + qm * 64 + mf * 16 + (lane >> 4) * 4 + rr);
                    #pragma unroll
                    for (int qn = 0; qn < 2; ++qn)
                        #pragma unroll
                        for (int nf = 0; nf < 2; ++nf)
                            C[row * ldc + n0 + wn * 64 + qn * 32 + nf * 16 + lr] =
                                (_Float16)(acc[qm * 4 + mf][qn * 2 + nf][rr] * scale);
                }
    } else if constexpr (OMODE == 1) {
        float* C = (float*)Cout + (size_t)bz * sCz;
        #pragma unroll
        for (int qm = 0; qm < 2; ++qm)
            #pragma unroll
            for (int mf = 0; mf < 4; ++mf)
                #pragma unroll
                for (int rr = 0; rr < 4; ++rr) {
                    size_t row = (size_t)(m0 + wm * 128 + qm * 64 + mf * 16 + (lane >> 4) * 4 + rr);
                    #pragma unroll
                    for (int qn = 0; qn < 2; ++qn)
                        #pragma unroll
                        for (int nf = 0; nf < 2; ++nf)
                            C[row * ldc + n0 + wn * 64 + qn * 32 + nf * 16 + lr] =
                                acc[qm * 4 + mf][qn * 2 + nf][rr] * scale;
                }
    } else {
        // Vt[b][e][t]: b = tile batch, e = out col, t = row % 2048
        _Float16* C = (_Float16*)Cout;
        const size_t bofs = (size_t)(m0 >> 11) * (1024ull * 2048ull);
        #pragma unroll
        for (int qn = 0; qn < 2; ++qn)
            #pragma unroll
            for (int nf = 0; nf < 2; ++nf) {
                size_t e = (size_t)(n0 + wn * 64 + qn * 32 + nf * 16 + lr);
                #pragma unroll
                for (int qm = 0; qm < 2; ++qm)
                    #pragma unroll
                    for (int mf = 0; mf < 4; ++mf) {
                        int t0 = (m0 + wm * 128 + qm * 64 + mf * 16 + (lane >> 4) * 4) & 2047;
                        half4 h;
                        #pragma unroll
                        for (int rr = 0; rr < 4; ++rr) h[rr] = (_Float16)acc[qm * 4 + mf][qn * 2 + nf][rr];
                        *(half4*)(C + bofs + e * 2048 + t0) = h;
                    }
            }
    }
}

// ---------------------------------------------------------------------------
// In-place row softmax on S fp16 [nrows][2048]; 1 wave per row.
// ---------------------------------------------------------------------------
__global__ void softmax_rows(_Float16* __restrict__ S)
{
    const int wid  = threadIdx.x >> 6;
    const int lane = threadIdx.x & 63;
    const size_t row = (size_t)blockIdx.x * 4 + wid;
    _Float16* p = S + row * 2048;

    float v[32];
    #pragma unroll
    for (int i = 0; i < 4; ++i) {
        half8 h = *(const half8*)(p + i * 512 + lane * 8);
        #pragma unroll
        for (int j = 0; j < 8; ++j) v[i * 8 + j] = (float)h[j];
    }
    float m = -1e30f;
    #pragma unroll
    for (int t = 0; t < 32; ++t) m = fmaxf(m, v[t]);
    #pragma unroll
    for (int mask = 1; mask < 64; mask <<= 1) m = fmaxf(m, __shfl_xor(m, mask));

    float s = 0.f;
    #pragma unroll
    for (int t = 0; t < 32; ++t) { v[t] = __expf(v[t] - m); s += v[t]; }
    #pragma unroll
    for (int mask = 1; mask < 64; mask <<= 1) s += __shfl_xor(s, mask);
    const float r = 1.0f / s;

    #pragma unroll
    for (int i = 0; i < 4; ++i) {
        half8 h;
        #pragma unroll
        for (int j = 0; j < 8; ++j) h[j] = (_Float16)(v[i * 8 + j] * r);
        *(half8*)(p + i * 512 + lane * 8) = h;
    }
}

// ---------------------------------------------------------------------------
extern "C" void kernel_launch(void* const* d_in, const int* in_sizes, int n_in,
                              void* d_out, int out_size, void* d_ws, size_t ws_size,
                              hipStream_t stream)
{
    const float* x1 = (const float*)d_in[0];
    const float* x2 = (const float*)d_in[1];
    // weights in d_in[2..7]: Wq1, Wk1, Wv1, Wq2, Wk2, Wv2

    char* ws = (char*)d_ws;
    _Float16* Wt  = (_Float16*)ws;                       // 12 MB (6 x 2 MB)
    _Float16* X1h = (_Float16*)(ws + 12582912L);         // 32 MB
    _Float16* X2h = (_Float16*)(ws + 12582912L + 33554432L);
    _Float16* Q   = (_Float16*)(ws + 12582912L + 2 * 33554432L);
    _Float16* Kk  = (_Float16*)(ws + 12582912L + 3 * 33554432L);
    _Float16* Vt  = (_Float16*)(ws + 12582912L + 4 * 33554432L);
    _Float16* S   = (_Float16*)(ws + 12582912L + 5 * 33554432L);  // 64 MB

    transpose_cast6<<<dim3(16, 16, 6), 256, 0, stream>>>(
        (const float*)d_in[2], (const float*)d_in[3], (const float*)d_in[4],
        (const float*)d_in[5], (const float*)d_in[6], (const float*)d_in[7], Wt);

    cast2_f32_f16<<<dim3(2048, 2), 256, 0, stream>>>(x1, x2, X1h, X2h);

    for (int d = 0; d < 2; ++d) {
        // d==0: context_vec_2 = attn(Q=x1·Wq1, K=x2·Wk2, V=x2·Wv2) -> out[16777216:]
        // d==1: context_vec_1 = attn(Q=x2·Wq2, K=x1·Wk1, V=x1·Wv1) -> out[0:]
        const _Float16* xq  = (d == 0) ? X1h : X2h;
        const _Float16* xkv = (d == 0) ? X2h : X1h;
        const _Float16* wtq = Wt + (size_t)((d == 0) ? 0 : 3) * 1048576;
        const _Float16* wtk = Wt + (size_t)((d == 0) ? 4 : 1) * 1048576;
        const _Float16* wtv = Wt + (size_t)((d == 0) ? 5 : 2) * 1048576;
        float* outp = (float*)d_out + ((d == 0) ? 16777216L : 0L);

        gemm8p<0><<<dim3(4, 64, 1), 512, 0, stream>>>(xq,  wtq, Q,  1024, 1024, 1024, 1024, 0, 0, 0, 1.f);
        gemm8p<0><<<dim3(4, 64, 1), 512, 0, stream>>>(xkv, wtk, Kk, 1024, 1024, 1024, 1024, 0, 0, 0, 1.f);
        gemm8p<2><<<dim3(4, 64, 1), 512, 0, stream>>>(xkv, wtv, Vt, 1024, 1024, 0,    1024, 0, 0, 0, 1.f);

        gemm8p<0><<<dim3(8, 8, 8), 512, 0, stream>>>(Q, Kk, S, 1024, 1024, 2048, 1024,
                                                     2048L * 1024, 2048L * 1024, 2048L * 2048, 0.03125f);
        softmax_rows<<<4096, 256, 0, stream>>>(S);

        gemm8p<1><<<dim3(4, 8, 8), 512, 0, stream>>>(S, Vt, outp, 2048, 2048, 1024, 2048,
                                                     2048L * 2048, 2048L * 1024, 2048L * 1024, 1.f);
    }
}